// Round 1
// baseline (165.820 us; speedup 1.0000x reference)
//
#include <hip/hip_runtime.h>

#define B_SZ 256
#define L_SZ 2048
#define T_SZ 32
#define NCH 16
#define CLEN 128   // L_SZ / NCH
#define START_IDX 0
#define STOP_IDX 1

typedef __attribute__((ext_vector_type(8))) short bf16x8;
typedef __attribute__((ext_vector_type(4))) float f32x4;

__device__ __forceinline__ unsigned fau(float f){ union{float f; unsigned u;} v; v.f=f; return v.u; }
__device__ __forceinline__ float uaf(unsigned u){ union{unsigned u; float f;} v; v.u=u; return v.f; }
// pack two fp32 -> bf16x2 dword by truncation (lo elem = low 16 bits)
__device__ __forceinline__ int pack_trunc(float lo, float hi){
  return (int)((fau(lo)>>16) | (fau(hi)&0xffff0000u));
}
__device__ __forceinline__ bf16x8 frag_of(const int* p){
  union{ int i[4]; bf16x8 v; } u;
  u.i[0]=p[0]; u.i[1]=p[1]; u.i[2]=p[2]; u.i[3]=p[3];
  return u.v;
}

__global__ void zero_kernel(float* out){ if(threadIdx.x==0) out[0]=0.f; }

__global__ __launch_bounds__(1024) void crf_loss_kernel(
    const float* __restrict__ efeats, const float* __restrict__ mask,
    const int* __restrict__ tgt, const float* __restrict__ trans,
    float* __restrict__ out)
{
  __shared__ float s_trans[T_SZ*T_SZ];          // raw transitions (gold + terminal + E-frags)
  __shared__ float s_d[NCH][T_SZ];              // per-wave d=exp(feat) broadcast buffer
  __shared__ unsigned short s_M[NCH][T_SZ*T_SZ];// chunk matrices bf16, layout [n*32 + s] (col-major)
  __shared__ int   s_es[NCH];
  __shared__ float s_gd[NCH];
  __shared__ float s_ml[NCH];

  const int tid  = threadIdx.x;
  const int b    = blockIdx.x;
  const int w    = tid >> 6;     // wave id = chunk id
  const int lane = tid & 63;
  const int g    = lane >> 4;    // quad 0..3
  const int c16  = lane & 15;
  const int i32  = lane & 31;

  s_trans[tid] = trans[tid];     // 1024 threads == 1024 elements
  __syncthreads();

  // ---- constant A-frags: E' = exp(trans) with row label s1(I,i)=8*(i>>2)+4I+(i&3)
  // A[m=lane&15][k=8*(lane>>4)+j], j=0..7
  int a0[4], a1[4];
  #pragma unroll
  for (int I=0; I<2; ++I){
    int row = 8*(c16>>2) + 4*I + (c16&3);
    float e[8];
    #pragma unroll
    for (int j=0;j<8;++j) e[j] = __expf(s_trans[row*T_SZ + 8*g + j]);
    int* dst = I ? a1 : a0;
    #pragma unroll
    for (int p=0;p<4;++p) dst[p] = pack_trunc(e[2*p], e[2*p+1]);
  }

  // ---- B-frags = identity (chunk matrix M starts as I)
  // B[k=8*g+j][n=16*J+c16]
  int b0[4], b1[4];
  #pragma unroll
  for (int p=0;p<4;++p){
    int s0 = 8*g + 2*p, s1 = s0+1;
    unsigned lo = (s0==c16)?0x3f80u:0u, hi = (s1==c16)?0x3f80u:0u;
    b0[p] = (int)(lo | (hi<<16));
    lo = (s0==16+c16)?0x3f80u:0u; hi = (s1==16+c16)?0x3f80u:0u;
    b1[p] = (int)(lo | (hi<<16));
  }

  const int l0 = w * CLEN;
  const long fbase = ((long)b * L_SZ) * T_SZ;

  float fq[4];
  #pragma unroll
  for (int i=0;i<4;++i) fq[i] = efeats[fbase + (long)(l0+i)*T_SZ + i32];

  int   tA = tgt [b*L_SZ + l0 + lane];
  int   tB = tgt [b*L_SZ + l0 + 64 + lane];
  float mA = mask[b*L_SZ + l0 + lane];
  float mB = mask[b*L_SZ + l0 + 64 + lane];
  int prev = (l0==0) ? START_IDX : tgt[b*L_SZ + l0 - 1];

  int esum = 0;
  float gold = 0.f, mlen = 0.f;
  const f32x4 zf = {0.f,0.f,0.f,0.f};

  #pragma unroll 4
  for (int t=0; t<CLEN; ++t){
    float fcur = fq[t&3];
    int lpf = l0 + t + 4; lpf = (lpf < L_SZ) ? lpf : (L_SZ-1);
    fq[t&3] = efeats[fbase + (long)lpf*T_SZ + i32];

    float mk  = uaf((unsigned)__builtin_amdgcn_readlane((int)fau((t<64)?mA:mB), t&63));
    int   cur = __builtin_amdgcn_readlane((t<64)?tA:tB, t&63);
    mlen += mk;

    if (mk > 0.f){
      if (lane < 32) s_d[w][lane] = __expf(fcur);   // d in tag order

      f32x4 c00 = __builtin_amdgcn_mfma_f32_16x16x32_bf16(frag_of(a0), frag_of(b0), zf, 0,0,0);
      f32x4 c01 = __builtin_amdgcn_mfma_f32_16x16x32_bf16(frag_of(a0), frag_of(b1), zf, 0,0,0);
      f32x4 c10 = __builtin_amdgcn_mfma_f32_16x16x32_bf16(frag_of(a1), frag_of(b0), zf, 0,0,0);
      f32x4 c11 = __builtin_amdgcn_mfma_f32_16x16x32_bf16(frag_of(a1), frag_of(b1), zf, 0,0,0);

      // per-lane needs d[8g .. 8g+7] (consecutive thanks to the row labeling)
      const float4* dv = (const float4*)(&s_d[w][0]);
      float4 dl = dv[2*g], dh = dv[2*g+1];
      float f0=dl.x, f1=dl.y, f2=dl.z, f3=dl.w;
      float f4=dh.x, f5=dh.y, f6=dh.z, f7=dh.w;

      // power-of-2 rescale from M[0][0] (lane0, c00 reg0, scaled by d[0])
      float m00 = c00[0]*f0;
      unsigned mb = (unsigned)__builtin_amdgcn_readfirstlane((int)fau(m00));
      int e = (int)((mb>>23)&255u) - 127;
      esum += e;
      float r = uaf((unsigned)(127-e)<<23);
      f0*=r; f1*=r; f2*=r; f3*=r; f4*=r; f5*=r; f6*=r; f7*=r;

      c00[0]*=f0; c00[1]*=f1; c00[2]*=f2; c00[3]*=f3;   // tile I=0 rows 8g+0..3
      c01[0]*=f0; c01[1]*=f1; c01[2]*=f2; c01[3]*=f3;
      c10[0]*=f4; c10[1]*=f5; c10[2]*=f6; c10[3]*=f7;   // tile I=1 rows 8g+4..7
      c11[0]*=f4; c11[1]*=f5; c11[2]*=f6; c11[3]*=f7;

      // next B-frags: slot j = 4*I + reg  (lane-identical remap)
      b0[0]=pack_trunc(c00[0],c00[1]); b0[1]=pack_trunc(c00[2],c00[3]);
      b0[2]=pack_trunc(c10[0],c10[1]); b0[3]=pack_trunc(c10[2],c10[3]);
      b1[0]=pack_trunc(c01[0],c01[1]); b1[1]=pack_trunc(c01[2],c01[3]);
      b1[2]=pack_trunc(c11[0],c11[1]); b1[3]=pack_trunc(c11[2],c11[3]);

      // gold score contribution (wave-uniform)
      float tp   = s_trans[cur*T_SZ + prev];
      float emit = uaf((unsigned)__builtin_amdgcn_readlane((int)fau(fcur), cur));
      gold += tp + emit;
    }
    prev = cur;
  }

  // ---- store chunk matrix (bf16) to LDS, layout [n][s]
  #pragma unroll
  for (int p=0;p<4;++p){
    int s = 8*g + 2*p;
    *(int*)((char*)(&s_M[w][0]) + (((long)(c16   )*T_SZ + s) * 2)) = b0[p];
    *(int*)((char*)(&s_M[w][0]) + (((long)(16+c16)*T_SZ + s) * 2)) = b1[p];
  }
  if (lane==0){ s_es[w]=esum; s_gd[w]=gold; s_ml[w]=mlen; }
  __syncthreads();

  // ---- combine phase: wave 0, lane s holds exp-space alpha v[s]
  if (w==0){
    int s = i32;
    float v = (s==START_IDX)?1.f:0.f;
    int E = 0;
    for (int c=0;c<NCH;++c){
      float u=0.f;
      #pragma unroll 8
      for (int k=0;k<T_SZ;++k){
        float mv = uaf(((unsigned)s_M[c][k*T_SZ + s])<<16);
        float vk = uaf((unsigned)__builtin_amdgcn_readlane((int)fau(v), k));
        u = fmaf(mv, vk, u);
      }
      unsigned ub = (unsigned)__builtin_amdgcn_readfirstlane((int)fau(u));
      int eu = (int)((ub>>23)&255u)-127;
      E += s_es[c] + eu;
      v = u * uaf((unsigned)(127-eu)<<23);
    }
    float term = v * __expf(s_trans[STOP_IDX*T_SZ + s]);
    #pragma unroll
    for (int off=16; off>0; off>>=1) term += __shfl_xor(term, off, 32);
    float fwd = (float)E * 0.69314718055994530942f + __logf(term);

    float gp = (s<NCH)? s_gd[s] : 0.f;
    float lp = (s<NCH)? s_ml[s] : 0.f;
    #pragma unroll
    for (int off=16; off>0; off>>=1){ gp += __shfl_xor(gp, off, 32); lp += __shfl_xor(lp, off, 32); }
    int len = (int)lp;
    int last_tag = (len==0)? START_IDX : tgt[b*L_SZ + (len-1)];
    float goldT = gp + s_trans[STOP_IDX*T_SZ + last_tag];
    if (tid==0) atomicAdd(out, (fwd - goldT) * (1.0f/B_SZ));
  }
}

extern "C" void kernel_launch(void* const* d_in, const int* in_sizes, int n_in,
                              void* d_out, int out_size, void* d_ws, size_t ws_size,
                              hipStream_t stream)
{
  const float* efeats = (const float*)d_in[0];
  const float* mask   = (const float*)d_in[1];
  const int*   tgt    = (const int*)d_in[2];
  const float* trans  = (const float*)d_in[3];
  float* out = (float*)d_out;

  zero_kernel<<<dim3(1), dim3(64), 0, stream>>>(out);
  crf_loss_kernel<<<dim3(B_SZ), dim3(1024), 0, stream>>>(efeats, mask, tgt, trans, out);
}

// Round 2
// 153.227 us; speedup vs baseline: 1.0822x; 1.0822x over previous
//
#include <hip/hip_runtime.h>

#define B_SZ 256
#define L_SZ 2048
#define T_SZ 32
#define START_IDX 0
#define STOP_IDX 1

// split config
#define CLEN 64         // steps per chunk (one wave)
#define NCHB 8          // chunks (waves) per block
#define NCH_SEQ 32      // chunks per sequence
#define NBLK_SEQ 4      // blocks per sequence
#define NCHUNK_TOT (B_SZ * NCH_SEQ)

// fallback (round-1) config
#define FB_NCH 16
#define FB_CLEN 128

typedef __attribute__((ext_vector_type(8))) short bf16x8;
typedef __attribute__((ext_vector_type(4))) float f32x4;

__device__ __forceinline__ unsigned fau(float f){ union{float f; unsigned u;} v; v.f=f; return v.u; }
__device__ __forceinline__ float uaf(unsigned u){ union{unsigned u; float f;} v; v.u=u; return v.f; }
// pack two fp32 -> bf16x2 dword by truncation: 1 v_perm_b32
__device__ __forceinline__ int pack_trunc(float lo, float hi){
  return (int)__builtin_amdgcn_perm(fau(hi), fau(lo), 0x07060302u);
}
__device__ __forceinline__ bf16x8 frag_of(const int* p){
  union{ int i[4]; bf16x8 v; } u;
  u.i[0]=p[0]; u.i[1]=p[1]; u.i[2]=p[2]; u.i[3]=p[3];
  return u.v;
}

__global__ void zero_kernel(float* out){ if(threadIdx.x==0) out[0]=0.f; }

// ===================== kernel 1: per-chunk transfer matrices =====================
__global__ __launch_bounds__(512, 8) void crf_chunk_kernel(
    const float* __restrict__ efeats, const float* __restrict__ mask,
    const int* __restrict__ tgt, const float* __restrict__ trans,
    unsigned short* __restrict__ wsM, int* __restrict__ wsE,
    float* __restrict__ wsG, float* __restrict__ wsL)
{
  __shared__ float s_trans[T_SZ*T_SZ];
  __shared__ float s_d[NCHB][128];      // double-buffered: [(p&1)*64 + step-half*32 + tag]

  const int tid  = threadIdx.x;
  const int w    = tid >> 6;
  const int lane = tid & 63;
  const int g    = lane >> 4;
  const int c16  = lane & 15;

  const int b  = blockIdx.x >> 2;
  const int q  = blockIdx.x & 3;
  const int c  = q*NCHB + w;           // chunk index within sequence 0..31
  const int l0 = c * CLEN;

  s_trans[tid]     = trans[tid];
  s_trans[tid+512] = trans[tid+512];
  __syncthreads();

  // ---- constant A-frags: rows permuted so C-layout == next B-layout lane-identically
  int a0[4], a1[4];
  #pragma unroll
  for (int I=0; I<2; ++I){
    int row = 8*(c16>>2) + 4*I + (c16&3);
    float e[8];
    #pragma unroll
    for (int j=0;j<8;++j) e[j] = __expf(s_trans[row*T_SZ + 8*g + j]);
    int* dst = I ? a1 : a0;
    #pragma unroll
    for (int p=0;p<4;++p) dst[p] = pack_trunc(e[2*p], e[2*p+1]);
  }

  // ---- B-frags = identity
  int b0[4], b1[4];
  #pragma unroll
  for (int p=0;p<4;++p){
    int s0 = 8*g + 2*p, s1 = s0+1;
    unsigned lo = (s0==c16)?0x3f80u:0u, hi = (s1==c16)?0x3f80u:0u;
    b0[p] = (int)(lo | (hi<<16));
    lo = (s0==16+c16)?0x3f80u:0u; hi = (s1==16+c16)?0x3f80u:0u;
    b1[p] = (int)(lo | (hi<<16));
  }

  const long fbase = ((long)b * L_SZ) * T_SZ;
  const int  mbase = b*L_SZ + l0;

  // ---- per-lane per-step data (lane <-> step l0+lane)
  float maskv = mask[mbase + lane];
  int   tcur  = tgt [mbase + lane];
  int   tprev;
  {
    int lp = (l0 + lane == 0) ? mbase : (mbase + lane - 1);
    tprev = tgt[lp];
    if (l0 + lane == 0) tprev = START_IDX;
  }

  // ---- gold score + mask length, lane-parallel (out of the serial loop)
  float emitg = efeats[fbase + (long)(l0+lane)*T_SZ + tcur];
  float gl = (maskv > 0.f) ? (s_trans[tcur*T_SZ + tprev] + emitg) : 0.f;
  float ml = maskv;
  #pragma unroll
  for (int off=32; off>0; off>>=1){ gl += __shfl_xor(gl, off, 64); ml += __shfl_xor(ml, off, 64); }

  unsigned long long mbits = __ballot(maskv > 0.f);

  // ---- feat pair prefetch: pair p = steps (2p, 2p+1) = 64 consecutive floats
  const float* fpt = efeats + fbase + (long)l0*T_SZ;
  float f0raw = fpt[lane];
  float fq[4];
  #pragma unroll
  for (int i=1; i<=4; ++i) fq[i&3] = fpt[i*64 + lane];
  s_d[w][lane] = __expf(f0raw);    // buffer 0 <- pair 0

  int esum = 0;
  const f32x4 zf = {0.f,0.f,0.f,0.f};

  #pragma unroll 4
  for (int p=0; p<32; ++p){
    // stage pair p+1 into the other buffer; refill prefetch slot with pair p+5
    if (p < 31){
      s_d[w][((p+1)&1)*64 + lane] = __expf(fq[(p+1)&3]);
      int np = p+5; if (np > 31) np = 31;
      fq[(p+1)&3] = fpt[np*64 + lane];
    }
    const float* dbase = &s_d[w][(p&1)*64];
    #pragma unroll
    for (int h=0; h<2; ++h){
      int t = 2*p + h;
      if ((mbits >> t) & 1ull){
        f32x4 c00 = __builtin_amdgcn_mfma_f32_16x16x32_bf16(frag_of(a0), frag_of(b0), zf, 0,0,0);
        f32x4 c01 = __builtin_amdgcn_mfma_f32_16x16x32_bf16(frag_of(a0), frag_of(b1), zf, 0,0,0);
        f32x4 c10 = __builtin_amdgcn_mfma_f32_16x16x32_bf16(frag_of(a1), frag_of(b0), zf, 0,0,0);
        f32x4 c11 = __builtin_amdgcn_mfma_f32_16x16x32_bf16(frag_of(a1), frag_of(b1), zf, 0,0,0);

        const float4* dv = (const float4*)(dbase + h*32);
        float4 dl = dv[2*g], dh = dv[2*g+1];
        float f0=dl.x, f1=dl.y, f2=dl.z, f3=dl.w;
        float f4=dh.x, f5=dh.y, f6=dh.z, f7=dh.w;

        if (h==1 && (p&1)==1){   // rescale every 4 steps (t%4==3); bounded growth fits fp32/bf16
          float m00 = c00[0]*f0;
          unsigned mb2 = (unsigned)__builtin_amdgcn_readfirstlane((int)fau(m00));
          int e = (int)((mb2>>23)&255u) - 127;
          esum += e;
          float r = uaf((unsigned)(127-e)<<23);
          f0*=r; f1*=r; f2*=r; f3*=r; f4*=r; f5*=r; f6*=r; f7*=r;
        }

        c00[0]*=f0; c00[1]*=f1; c00[2]*=f2; c00[3]*=f3;
        c01[0]*=f0; c01[1]*=f1; c01[2]*=f2; c01[3]*=f3;
        c10[0]*=f4; c10[1]*=f5; c10[2]*=f6; c10[3]*=f7;
        c11[0]*=f4; c11[1]*=f5; c11[2]*=f6; c11[3]*=f7;

        b0[0]=pack_trunc(c00[0],c00[1]); b0[1]=pack_trunc(c00[2],c00[3]);
        b0[2]=pack_trunc(c10[0],c10[1]); b0[3]=pack_trunc(c10[2],c10[3]);
        b1[0]=pack_trunc(c01[0],c01[1]); b1[1]=pack_trunc(c01[2],c01[3]);
        b1[2]=pack_trunc(c11[0],c11[1]); b1[3]=pack_trunc(c11[2],c11[3]);
      }
    }
  }

  // ---- write chunk matrix (bf16, layout [n*32+k]) + scalars to workspace
  unsigned short* Mptr = wsM + (long)(b*NCH_SEQ + c) * (T_SZ*T_SZ);
  #pragma unroll
  for (int pp=0; pp<4; ++pp){
    int s = 8*g + 2*pp;
    *(int*)((char*)Mptr + ((c16*T_SZ + s)*2))        = b0[pp];
    *(int*)((char*)Mptr + (((16+c16)*T_SZ + s)*2))   = b1[pp];
  }
  if (lane==0){
    int cg = b*NCH_SEQ + c;
    wsE[cg]=esum; wsG[cg]=gl; wsL[cg]=ml;
  }
}

// ===================== kernel 2: combine 32 chunks per sequence =====================
__global__ __launch_bounds__(256) void crf_combine_kernel(
    const unsigned short* __restrict__ wsM, const int* __restrict__ wsE,
    const float* __restrict__ wsG, const float* __restrict__ wsL,
    const int* __restrict__ tgt, const float* __restrict__ trans,
    float* __restrict__ out)
{
  __shared__ unsigned short sM[NCH_SEQ*T_SZ*T_SZ];   // 64 KiB
  __shared__ int   s_es[NCH_SEQ];
  __shared__ float s_g[NCH_SEQ], s_ml[NCH_SEQ];

  const int tid = threadIdx.x;
  const int b   = blockIdx.x;

  const uint4* src = (const uint4*)(wsM + (long)b*NCH_SEQ*T_SZ*T_SZ);
  uint4* dst = (uint4*)sM;
  #pragma unroll
  for (int i=0;i<16;++i) dst[tid + i*256] = src[tid + i*256];
  if (tid < NCH_SEQ){
    s_es[tid]=wsE[b*NCH_SEQ+tid]; s_g[tid]=wsG[b*NCH_SEQ+tid]; s_ml[tid]=wsL[b*NCH_SEQ+tid];
  }
  __syncthreads();

  if (tid < 64){
    int s = tid & 31;
    float v = (s==START_IDX)?1.f:0.f;
    int E = 0;
    for (int cc=0; cc<NCH_SEQ; ++cc){
      const unsigned short* M = &sM[cc*T_SZ*T_SZ];
      float u = 0.f;
      #pragma unroll 8
      for (int k=0;k<T_SZ;++k){
        float mv = uaf(((unsigned)M[k*T_SZ + s])<<16);
        float vk = uaf((unsigned)__builtin_amdgcn_readlane((int)fau(v), k));
        u = fmaf(mv, vk, u);
      }
      unsigned ub = (unsigned)__builtin_amdgcn_readfirstlane((int)fau(u));
      int eu = (int)((ub>>23)&255u)-127;
      E += s_es[cc] + eu;
      v = u * uaf((unsigned)(127-eu)<<23);
    }
    float term = v * __expf(trans[STOP_IDX*T_SZ + s]);
    #pragma unroll
    for (int off=16; off>0; off>>=1) term += __shfl_xor(term, off, 32);
    float fwd = (float)E * 0.69314718055994530942f + __logf(term);

    float gp = s_g[s];
    float lp = s_ml[s];
    #pragma unroll
    for (int off=16; off>0; off>>=1){ gp += __shfl_xor(gp, off, 32); lp += __shfl_xor(lp, off, 32); }
    int len = (int)lp;
    int last_tag = (len==0)? START_IDX : tgt[b*L_SZ + len-1];
    float goldT = gp + trans[STOP_IDX*T_SZ + last_tag];
    if (tid==0) atomicAdd(out, (fwd - goldT) * (1.0f/B_SZ));
  }
}

// ===================== fallback: round-1 single kernel (no workspace) =====================
__global__ __launch_bounds__(1024) void crf_loss_kernel(
    const float* __restrict__ efeats, const float* __restrict__ mask,
    const int* __restrict__ tgt, const float* __restrict__ trans,
    float* __restrict__ out)
{
  __shared__ float s_trans[T_SZ*T_SZ];
  __shared__ float s_d[FB_NCH][T_SZ];
  __shared__ unsigned short s_M[FB_NCH][T_SZ*T_SZ];
  __shared__ int   s_es[FB_NCH];
  __shared__ float s_gd[FB_NCH];
  __shared__ float s_mlv[FB_NCH];

  const int tid  = threadIdx.x;
  const int b    = blockIdx.x;
  const int w    = tid >> 6;
  const int lane = tid & 63;
  const int g    = lane >> 4;
  const int c16  = lane & 15;
  const int i32  = lane & 31;

  s_trans[tid] = trans[tid];
  __syncthreads();

  int a0[4], a1[4];
  #pragma unroll
  for (int I=0; I<2; ++I){
    int row = 8*(c16>>2) + 4*I + (c16&3);
    float e[8];
    #pragma unroll
    for (int j=0;j<8;++j) e[j] = __expf(s_trans[row*T_SZ + 8*g + j]);
    int* dst = I ? a1 : a0;
    #pragma unroll
    for (int p=0;p<4;++p) dst[p] = pack_trunc(e[2*p], e[2*p+1]);
  }

  int b0[4], b1[4];
  #pragma unroll
  for (int p=0;p<4;++p){
    int s0 = 8*g + 2*p, s1 = s0+1;
    unsigned lo = (s0==c16)?0x3f80u:0u, hi = (s1==c16)?0x3f80u:0u;
    b0[p] = (int)(lo | (hi<<16));
    lo = (s0==16+c16)?0x3f80u:0u; hi = (s1==16+c16)?0x3f80u:0u;
    b1[p] = (int)(lo | (hi<<16));
  }

  const int l0 = w * FB_CLEN;
  const long fbase = ((long)b * L_SZ) * T_SZ;

  float fqv[4];
  #pragma unroll
  for (int i=0;i<4;++i) fqv[i] = efeats[fbase + (long)(l0+i)*T_SZ + i32];

  int   tA = tgt [b*L_SZ + l0 + lane];
  int   tB = tgt [b*L_SZ + l0 + 64 + lane];
  float mA = mask[b*L_SZ + l0 + lane];
  float mB = mask[b*L_SZ + l0 + 64 + lane];
  int prev = (l0==0) ? START_IDX : tgt[b*L_SZ + l0 - 1];

  int esum = 0;
  float gold = 0.f, mlen = 0.f;
  const f32x4 zf = {0.f,0.f,0.f,0.f};

  #pragma unroll 4
  for (int t=0; t<FB_CLEN; ++t){
    float fcur = fqv[t&3];
    int lpf = l0 + t + 4; lpf = (lpf < L_SZ) ? lpf : (L_SZ-1);
    fqv[t&3] = efeats[fbase + (long)lpf*T_SZ + i32];

    float mk  = uaf((unsigned)__builtin_amdgcn_readlane((int)fau((t<64)?mA:mB), t&63));
    int   cur = __builtin_amdgcn_readlane((t<64)?tA:tB, t&63);
    mlen += mk;

    if (mk > 0.f){
      if (lane < 32) s_d[w][lane] = __expf(fcur);

      f32x4 c00 = __builtin_amdgcn_mfma_f32_16x16x32_bf16(frag_of(a0), frag_of(b0), zf, 0,0,0);
      f32x4 c01 = __builtin_amdgcn_mfma_f32_16x16x32_bf16(frag_of(a0), frag_of(b1), zf, 0,0,0);
      f32x4 c10 = __builtin_amdgcn_mfma_f32_16x16x32_bf16(frag_of(a1), frag_of(b0), zf, 0,0,0);
      f32x4 c11 = __builtin_amdgcn_mfma_f32_16x16x32_bf16(frag_of(a1), frag_of(b1), zf, 0,0,0);

      const float4* dv = (const float4*)(&s_d[w][0]);
      float4 dl = dv[2*g], dh = dv[2*g+1];
      float f0=dl.x, f1=dl.y, f2=dl.z, f3=dl.w;
      float f4=dh.x, f5=dh.y, f6=dh.z, f7=dh.w;

      float m00 = c00[0]*f0;
      unsigned mb = (unsigned)__builtin_amdgcn_readfirstlane((int)fau(m00));
      int e = (int)((mb>>23)&255u) - 127;
      esum += e;
      float r = uaf((unsigned)(127-e)<<23);
      f0*=r; f1*=r; f2*=r; f3*=r; f4*=r; f5*=r; f6*=r; f7*=r;

      c00[0]*=f0; c00[1]*=f1; c00[2]*=f2; c00[3]*=f3;
      c01[0]*=f0; c01[1]*=f1; c01[2]*=f2; c01[3]*=f3;
      c10[0]*=f4; c10[1]*=f5; c10[2]*=f6; c10[3]*=f7;
      c11[0]*=f4; c11[1]*=f5; c11[2]*=f6; c11[3]*=f7;

      b0[0]=pack_trunc(c00[0],c00[1]); b0[1]=pack_trunc(c00[2],c00[3]);
      b0[2]=pack_trunc(c10[0],c10[1]); b0[3]=pack_trunc(c10[2],c10[3]);
      b1[0]=pack_trunc(c01[0],c01[1]); b1[1]=pack_trunc(c01[2],c01[3]);
      b1[2]=pack_trunc(c11[0],c11[1]); b1[3]=pack_trunc(c11[2],c11[3]);

      float tp   = s_trans[cur*T_SZ + prev];
      float emit = uaf((unsigned)__builtin_amdgcn_readlane((int)fau(fcur), cur));
      gold += tp + emit;
    }
    prev = cur;
  }

  #pragma unroll
  for (int p=0;p<4;++p){
    int s = 8*g + 2*p;
    *(int*)((char*)(&s_M[w][0]) + (((long)(c16   )*T_SZ + s) * 2)) = b0[p];
    *(int*)((char*)(&s_M[w][0]) + (((long)(16+c16)*T_SZ + s) * 2)) = b1[p];
  }
  if (lane==0){ s_es[w]=esum; s_gd[w]=gold; s_mlv[w]=mlen; }
  __syncthreads();

  if (w==0){
    int s = i32;
    float v = (s==START_IDX)?1.f:0.f;
    int E = 0;
    for (int c=0;c<FB_NCH;++c){
      float u=0.f;
      #pragma unroll 8
      for (int k=0;k<T_SZ;++k){
        float mv = uaf(((unsigned)s_M[c][k*T_SZ + s])<<16);
        float vk = uaf((unsigned)__builtin_amdgcn_readlane((int)fau(v), k));
        u = fmaf(mv, vk, u);
      }
      unsigned ub = (unsigned)__builtin_amdgcn_readfirstlane((int)fau(u));
      int eu = (int)((ub>>23)&255u)-127;
      E += s_es[c] + eu;
      v = u * uaf((unsigned)(127-eu)<<23);
    }
    float term = v * __expf(s_trans[STOP_IDX*T_SZ + s]);
    #pragma unroll
    for (int off=16; off>0; off>>=1) term += __shfl_xor(term, off, 32);
    float fwd = (float)E * 0.69314718055994530942f + __logf(term);

    float gp = (s<FB_NCH)? s_gd[s] : 0.f;
    float lp = (s<FB_NCH)? s_mlv[s] : 0.f;
    #pragma unroll
    for (int off=16; off>0; off>>=1){ gp += __shfl_xor(gp, off, 32); lp += __shfl_xor(lp, off, 32); }
    int len = (int)lp;
    int last_tag = (len==0)? START_IDX : tgt[b*L_SZ + (len-1)];
    float goldT = gp + s_trans[STOP_IDX*T_SZ + last_tag];
    if (tid==0) atomicAdd(out, (fwd - goldT) * (1.0f/B_SZ));
  }
}

extern "C" void kernel_launch(void* const* d_in, const int* in_sizes, int n_in,
                              void* d_out, int out_size, void* d_ws, size_t ws_size,
                              hipStream_t stream)
{
  const float* efeats = (const float*)d_in[0];
  const float* mask   = (const float*)d_in[1];
  const int*   tgt    = (const int*)d_in[2];
  const float* trans  = (const float*)d_in[3];
  float* out = (float*)d_out;

  const size_t needM = (size_t)NCHUNK_TOT * T_SZ * T_SZ * 2;   // 16 MiB
  const size_t need  = needM + (size_t)NCHUNK_TOT * 12;

  zero_kernel<<<dim3(1), dim3(64), 0, stream>>>(out);

  if (ws_size >= need){
    unsigned short* wsM = (unsigned short*)d_ws;
    char* p = (char*)d_ws + needM;
    int*   wsE = (int*)p;
    float* wsG = (float*)(p + (size_t)NCHUNK_TOT*4);
    float* wsL = (float*)(p + (size_t)NCHUNK_TOT*8);
    crf_chunk_kernel<<<dim3(B_SZ*NBLK_SEQ), dim3(512), 0, stream>>>(
        efeats, mask, tgt, trans, wsM, wsE, wsG, wsL);
    crf_combine_kernel<<<dim3(B_SZ), dim3(256), 0, stream>>>(
        wsM, wsE, wsG, wsL, tgt, trans, out);
  } else {
    crf_loss_kernel<<<dim3(B_SZ), dim3(1024), 0, stream>>>(efeats, mask, tgt, trans, out);
  }
}

// Round 3
// 142.541 us; speedup vs baseline: 1.1633x; 1.0750x over previous
//
#include <hip/hip_runtime.h>

#define B_SZ 256
#define L_SZ 2048
#define T_SZ 32
#define START_IDX 0
#define STOP_IDX 1

// split config
#define CLEN 64         // steps per chunk (one wave)
#define NCHB 8          // chunks (waves) per block
#define NCH_SEQ 32      // chunks per sequence
#define NBLK_SEQ 4      // blocks per sequence
#define NBLK_TOT (B_SZ * NBLK_SEQ)

// fallback (round-1) config
#define FB_NCH 16
#define FB_CLEN 128

typedef __attribute__((ext_vector_type(8))) short bf16x8;
typedef __attribute__((ext_vector_type(4))) float f32x4;
typedef __attribute__((ext_vector_type(2))) float f32x2;

__device__ __forceinline__ unsigned fau(float f){ union{float f; unsigned u;} v; v.f=f; return v.u; }
__device__ __forceinline__ float uaf(unsigned u){ union{unsigned u; float f;} v; v.u=u; return v.f; }
// pack two fp32 -> bf16x2 dword by truncation: 1 v_perm_b32
__device__ __forceinline__ int pack_trunc(float lo, float hi){
  return (int)__builtin_amdgcn_perm(fau(hi), fau(lo), 0x07060302u);
}
__device__ __forceinline__ bf16x8 frag_of(const int* p){
  union{ int i[4]; bf16x8 v; } u;
  u.i[0]=p[0]; u.i[1]=p[1]; u.i[2]=p[2]; u.i[3]=p[3];
  return u.v;
}

__global__ void zero_kernel(float* out){ if(threadIdx.x==0) out[0]=0.f; }

// ---- 32x32 matrix product Q = L x Rt using standard 16x16x32 frag layouts.
// L in row-major R-layout [x*32+m], Rt in transposed T-layout [y*32+m].
// Q written to dst: writeT ? T-layout [y*32+x] : R-layout [x*32+y].
// All entries strictly positive; renormalized by 2^-e (e returned).
__device__ __forceinline__ int mat_prod(const unsigned short* L, const unsigned short* Rt,
                                        unsigned short* dst, bool writeT, int lane)
{
  const int g = lane >> 4, c16 = lane & 15;
  const int ko = 8*g;
  bf16x8 A0 = *(const bf16x8*)(L  + (c16*T_SZ      + ko));
  bf16x8 A1 = *(const bf16x8*)(L  + ((16+c16)*T_SZ + ko));
  bf16x8 B0 = *(const bf16x8*)(Rt + (c16*T_SZ      + ko));
  bf16x8 B1 = *(const bf16x8*)(Rt + ((16+c16)*T_SZ + ko));
  const f32x4 zf = {0.f,0.f,0.f,0.f};
  f32x4 q00 = __builtin_amdgcn_mfma_f32_16x16x32_bf16(A0, B0, zf, 0,0,0); // x-tile0,y-tile0
  f32x4 q01 = __builtin_amdgcn_mfma_f32_16x16x32_bf16(A0, B1, zf, 0,0,0); // x0,y1
  f32x4 q10 = __builtin_amdgcn_mfma_f32_16x16x32_bf16(A1, B0, zf, 0,0,0); // x1,y0
  f32x4 q11 = __builtin_amdgcn_mfma_f32_16x16x32_bf16(A1, B1, zf, 0,0,0); // x1,y1

  unsigned mb = (unsigned)__builtin_amdgcn_readfirstlane((int)fau(q00[0]));
  int e = (int)((mb>>23)&255u) - 127;
  float r = uaf((unsigned)(127-e)<<23);
  #pragma unroll
  for (int i=0;i<4;++i){ q00[i]*=r; q01[i]*=r; q10[i]*=r; q11[i]*=r; }

  if (!writeT){
    // C: x = I*16 + 4g + reg, y = J*16 + c16 -> scattered u16 writes
    #pragma unroll
    for (int reg=0; reg<4; ++reg){
      int x0 = 4*g + reg, x1 = 16 + 4*g + reg;
      dst[x0*T_SZ + c16]      = (unsigned short)(fau(q00[reg])>>16);
      dst[x0*T_SZ + 16 + c16] = (unsigned short)(fau(q01[reg])>>16);
      dst[x1*T_SZ + c16]      = (unsigned short)(fau(q10[reg])>>16);
      dst[x1*T_SZ + 16 + c16] = (unsigned short)(fau(q11[reg])>>16);
    }
  } else {
    // T[y*32+x]: consecutive reg -> consecutive x -> dword writes
    #pragma unroll
    for (int rp=0; rp<2; ++rp){
      int xb0 = 4*g + 2*rp, xb1 = 16 + 4*g + 2*rp;
      *(int*)&dst[c16*T_SZ + xb0]        = pack_trunc(q00[2*rp], q00[2*rp+1]);
      *(int*)&dst[(16+c16)*T_SZ + xb0]   = pack_trunc(q01[2*rp], q01[2*rp+1]);
      *(int*)&dst[c16*T_SZ + xb1]        = pack_trunc(q10[2*rp], q10[2*rp+1]);
      *(int*)&dst[(16+c16)*T_SZ + xb1]   = pack_trunc(q11[2*rp], q11[2*rp+1]);
    }
  }
  return e;
}

// ===================== kernel 1: per-chunk transfer matrices + in-block tree =====================
__global__ __launch_bounds__(512, 6) void crf_chunk_kernel(
    const float* __restrict__ efeats, const float* __restrict__ mask,
    const int* __restrict__ tgt, const float* __restrict__ trans,
    unsigned short* __restrict__ wsM, int* __restrict__ wsE,
    float* __restrict__ wsG, float* __restrict__ wsL)
{
  __shared__ float s_trans[T_SZ*T_SZ];
  __shared__ float s_d[NCHB][128];                 // double-buffered exp(feat) pairs
  __shared__ unsigned short s_tree[NCHB][T_SZ*T_SZ]; // 8 slots x 2KB
  __shared__ int   s_et[NCHB];
  __shared__ float s_gd[NCHB], s_ml[NCHB];

  const int tid  = threadIdx.x;
  const int w    = tid >> 6;
  const int lane = tid & 63;
  const int g    = lane >> 4;
  const int c16  = lane & 15;

  const int b  = blockIdx.x >> 2;
  const int q  = blockIdx.x & 3;
  const int c  = q*NCHB + w;
  const int l0 = c * CLEN;

  s_trans[tid]     = trans[tid];
  s_trans[tid+512] = trans[tid+512];
  __syncthreads();

  // ---- constant A-frags (sigma-relabeled rows)
  int a0[4], a1[4];
  #pragma unroll
  for (int I=0; I<2; ++I){
    int row = 8*(c16>>2) + 4*I + (c16&3);
    float e[8];
    #pragma unroll
    for (int j=0;j<8;++j) e[j] = __expf(s_trans[row*T_SZ + 8*g + j]);
    int* dst = I ? a1 : a0;
    #pragma unroll
    for (int p=0;p<4;++p) dst[p] = pack_trunc(e[2*p], e[2*p+1]);
  }

  // ---- B-frags = identity
  int b0[4], b1[4];
  #pragma unroll
  for (int p=0;p<4;++p){
    int s0 = 8*g + 2*p, s1 = s0+1;
    unsigned lo = (s0==c16)?0x3f80u:0u, hi = (s1==c16)?0x3f80u:0u;
    b0[p] = (int)(lo | (hi<<16));
    lo = (s0==16+c16)?0x3f80u:0u; hi = (s1==16+c16)?0x3f80u:0u;
    b1[p] = (int)(lo | (hi<<16));
  }

  const long fbase = ((long)b * L_SZ) * T_SZ;
  const int  mbase = b*L_SZ + l0;

  float maskv = mask[mbase + lane];
  int   tcur  = tgt [mbase + lane];
  int   tprev;
  {
    int lp = (l0 + lane == 0) ? mbase : (mbase + lane - 1);
    tprev = tgt[lp];
    if (l0 + lane == 0) tprev = START_IDX;
  }

  // gold + length, lane-parallel
  float emitg = efeats[fbase + (long)(l0+lane)*T_SZ + tcur];
  float gl = (maskv > 0.f) ? (s_trans[tcur*T_SZ + tprev] + emitg) : 0.f;
  float ml = maskv;
  #pragma unroll
  for (int off=32; off>0; off>>=1){ gl += __shfl_xor(gl, off, 64); ml += __shfl_xor(ml, off, 64); }

  unsigned long long mbits = __ballot(maskv > 0.f);

  const float* fpt = efeats + fbase + (long)l0*T_SZ;
  float f0raw = fpt[lane];
  float fq[4];
  #pragma unroll
  for (int i=1; i<=4; ++i) fq[i&3] = fpt[i*64 + lane];
  s_d[w][lane] = __expf(f0raw);

  int esum = 0;
  const f32x4 zf = {0.f,0.f,0.f,0.f};

  if (mbits == ~0ull){
    // ================= HOT: branchless straight-line =================
    #pragma unroll 2
    for (int p=0; p<32; ++p){
      s_d[w][((p+1)&1)*64 + lane] = __expf(fq[(p+1)&3]);
      int np = p+5; np = (np>31)?31:np;
      fq[(p+1)&3] = fpt[np*64 + lane];
      const float* dbase = &s_d[w][(p&1)*64];
      #pragma unroll
      for (int h=0; h<2; ++h){
        f32x4 c00 = __builtin_amdgcn_mfma_f32_16x16x32_bf16(frag_of(a0), frag_of(b0), zf, 0,0,0);
        f32x4 c01 = __builtin_amdgcn_mfma_f32_16x16x32_bf16(frag_of(a0), frag_of(b1), zf, 0,0,0);
        f32x4 c10 = __builtin_amdgcn_mfma_f32_16x16x32_bf16(frag_of(a1), frag_of(b0), zf, 0,0,0);
        f32x4 c11 = __builtin_amdgcn_mfma_f32_16x16x32_bf16(frag_of(a1), frag_of(b1), zf, 0,0,0);

        const float4* dv = (const float4*)(dbase + h*32);
        float4 dl = dv[2*g], dh2 = dv[2*g+1];
        f32x2 d01 = {dl.x, dl.y}, d23 = {dl.z, dl.w};
        f32x2 d45 = {dh2.x, dh2.y}, d67 = {dh2.z, dh2.w};

        if (h==1 && (p&1)==1){   // rescale every 4 steps
          float m00 = c00[0]*d01[0];
          unsigned mb2 = (unsigned)__builtin_amdgcn_readfirstlane((int)fau(m00));
          int e = (int)((mb2>>23)&255u) - 127;
          esum += e;
          float rr = uaf((unsigned)(127-e)<<23);
          f32x2 rv = {rr, rr};
          d01 *= rv; d23 *= rv; d45 *= rv; d67 *= rv;
        }

        f32x2 p00 = {c00[0],c00[1]}; p00 *= d01;
        f32x2 p01 = {c00[2],c00[3]}; p01 *= d23;
        f32x2 p10 = {c01[0],c01[1]}; p10 *= d01;
        f32x2 p11 = {c01[2],c01[3]}; p11 *= d23;
        f32x2 p20 = {c10[0],c10[1]}; p20 *= d45;
        f32x2 p21 = {c10[2],c10[3]}; p21 *= d67;
        f32x2 p30 = {c11[0],c11[1]}; p30 *= d45;
        f32x2 p31 = {c11[2],c11[3]}; p31 *= d67;

        b0[0]=pack_trunc(p00[0],p00[1]); b0[1]=pack_trunc(p01[0],p01[1]);
        b0[2]=pack_trunc(p20[0],p20[1]); b0[3]=pack_trunc(p21[0],p21[1]);
        b1[0]=pack_trunc(p10[0],p10[1]); b1[1]=pack_trunc(p11[0],p11[1]);
        b1[2]=pack_trunc(p30[0],p30[1]); b1[3]=pack_trunc(p31[0],p31[1]);
      }
    }
  } else {
    // ================= COLD: guarded (arbitrary mask) =================
    #pragma unroll 2
    for (int p=0; p<32; ++p){
      if (p < 31){
        s_d[w][((p+1)&1)*64 + lane] = __expf(fq[(p+1)&3]);
        int np = p+5; if (np > 31) np = 31;
        fq[(p+1)&3] = fpt[np*64 + lane];
      }
      const float* dbase = &s_d[w][(p&1)*64];
      #pragma unroll
      for (int h=0; h<2; ++h){
        int t = 2*p + h;
        if ((mbits >> t) & 1ull){
          f32x4 c00 = __builtin_amdgcn_mfma_f32_16x16x32_bf16(frag_of(a0), frag_of(b0), zf, 0,0,0);
          f32x4 c01 = __builtin_amdgcn_mfma_f32_16x16x32_bf16(frag_of(a0), frag_of(b1), zf, 0,0,0);
          f32x4 c10 = __builtin_amdgcn_mfma_f32_16x16x32_bf16(frag_of(a1), frag_of(b0), zf, 0,0,0);
          f32x4 c11 = __builtin_amdgcn_mfma_f32_16x16x32_bf16(frag_of(a1), frag_of(b1), zf, 0,0,0);

          const float4* dv = (const float4*)(dbase + h*32);
          float4 dl = dv[2*g], dh2 = dv[2*g+1];
          float f0=dl.x, f1=dl.y, f2=dl.z, f3=dl.w;
          float f4=dh2.x, f5=dh2.y, f6=dh2.z, f7=dh2.w;

          if (h==1 && (p&1)==1){
            float m00 = c00[0]*f0;
            unsigned mb2 = (unsigned)__builtin_amdgcn_readfirstlane((int)fau(m00));
            int e = (int)((mb2>>23)&255u) - 127;
            esum += e;
            float rr = uaf((unsigned)(127-e)<<23);
            f0*=rr; f1*=rr; f2*=rr; f3*=rr; f4*=rr; f5*=rr; f6*=rr; f7*=rr;
          }

          c00[0]*=f0; c00[1]*=f1; c00[2]*=f2; c00[3]*=f3;
          c01[0]*=f0; c01[1]*=f1; c01[2]*=f2; c01[3]*=f3;
          c10[0]*=f4; c10[1]*=f5; c10[2]*=f6; c10[3]*=f7;
          c11[0]*=f4; c11[1]*=f5; c11[2]*=f6; c11[3]*=f7;

          b0[0]=pack_trunc(c00[0],c00[1]); b0[1]=pack_trunc(c00[2],c00[3]);
          b0[2]=pack_trunc(c10[0],c10[1]); b0[3]=pack_trunc(c10[2],c10[3]);
          b1[0]=pack_trunc(c01[0],c01[1]); b1[1]=pack_trunc(c01[2],c01[3]);
          b1[2]=pack_trunc(c11[0],c11[1]); b1[3]=pack_trunc(c11[2],c11[3]);
        }
      }
    }
  }

  // ---- write own matrix to tree slot w: even wave -> R layout [x*32+y], odd -> T layout [y*32+x]
  // (x = prev-state = n-dim (c16 / 16+c16), y = new-state = k-slot s)
  if ((w & 1) == 0){
    unsigned short* R = &s_tree[w][0];
    #pragma unroll
    for (int p=0;p<4;++p){
      int s = 8*g + 2*p;
      *(int*)&R[c16*T_SZ + s]      = b0[p];
      *(int*)&R[(16+c16)*T_SZ + s] = b1[p];
    }
  } else {
    unsigned short* T = &s_tree[w][0];
    #pragma unroll
    for (int p=0;p<4;++p){
      int s = 8*g + 2*p;
      T[s*T_SZ + c16]           = (unsigned short)(b0[p] & 0xffff);
      T[(s+1)*T_SZ + c16]       = (unsigned short)(((unsigned)b0[p])>>16);
      T[s*T_SZ + 16 + c16]      = (unsigned short)(b1[p] & 0xffff);
      T[(s+1)*T_SZ + 16 + c16]  = (unsigned short)(((unsigned)b1[p])>>16);
    }
  }
  if (lane==0){ s_et[w]=esum; s_gd[w]=gl; s_ml[w]=ml; }
  __syncthreads();

  // ---- level 1: 4 pair products (earlier chunk = A/R side, later = B/T side)
  if (w < 4){
    int e = mat_prod(&s_tree[2*w][0], &s_tree[2*w+1][0], &s_tree[2*w][0], (w&1)!=0, lane);
    if (lane==0) s_et[2*w] = s_et[2*w] + s_et[2*w+1] + e;
  }
  __syncthreads();
  // ---- level 2
  if (w < 2){
    int e = mat_prod(&s_tree[4*w][0], &s_tree[4*w+2][0], &s_tree[4*w][0], (w&1)!=0, lane);
    if (lane==0) s_et[4*w] = s_et[4*w] + s_et[4*w+2] + e;
  }
  __syncthreads();
  // ---- level 3
  if (w == 0){
    int e = mat_prod(&s_tree[0][0], &s_tree[4][0], &s_tree[0][0], false, lane);
    if (lane==0) s_et[0] = s_et[0] + s_et[4] + e;
  }
  __syncthreads();

  // ---- export block matrix (R layout) + scalars
  const int bid = blockIdx.x;   // = b*4 + q
  ((int*)(wsM + (long)bid*(T_SZ*T_SZ)))[tid] = ((const int*)&s_tree[0][0])[tid];
  if (tid == 0){
    wsE[bid] = s_et[0];
    float gs=0.f, ls=0.f;
    #pragma unroll
    for (int i=0;i<NCHB;++i){ gs += s_gd[i]; ls += s_ml[i]; }
    wsG[bid] = gs; wsL[bid] = ls;
  }
}

// ===================== kernel 2: combine 4 block-matrices per sequence =====================
__global__ __launch_bounds__(64) void crf_combine_kernel(
    const unsigned short* __restrict__ wsM, const int* __restrict__ wsE,
    const float* __restrict__ wsG, const float* __restrict__ wsL,
    const int* __restrict__ tgt, const float* __restrict__ trans,
    float* __restrict__ out)
{
  __shared__ unsigned short sM[NBLK_SEQ*T_SZ*T_SZ];   // 8 KiB
  __shared__ float s_v[T_SZ];

  const int tid = threadIdx.x;
  const int b   = blockIdx.x;

  const uint4* src = (const uint4*)(wsM + (long)b*NBLK_SEQ*T_SZ*T_SZ);
  #pragma unroll
  for (int i=0;i<8;++i) ((uint4*)sM)[tid + i*64] = src[tid + i*64];
  __syncthreads();

  const int s = tid & 31;
  float v = (s==START_IDX)?1.f:0.f;
  int E = 0;
  #pragma unroll
  for (int j=0; j<NBLK_SEQ; ++j){
    if (tid < 32) s_v[s] = v;
    __syncthreads();
    const unsigned short* M = &sM[j*T_SZ*T_SZ];
    float u = 0.f;
    #pragma unroll 8
    for (int x=0; x<T_SZ; ++x){
      float mv = uaf(((unsigned)M[x*T_SZ + s])<<16);
      u = fmaf(mv, s_v[x], u);
    }
    unsigned ub = (unsigned)__builtin_amdgcn_readfirstlane((int)fau(u));
    int eu = (int)((ub>>23)&255u)-127;
    E += wsE[b*NBLK_SEQ + j] + eu;
    v = u * uaf((unsigned)(127-eu)<<23);
    __syncthreads();
  }
  float term = v * __expf(trans[STOP_IDX*T_SZ + s]);
  #pragma unroll
  for (int off=16; off>0; off>>=1) term += __shfl_xor(term, off, 32);
  float fwd = (float)E * 0.69314718055994530942f + __logf(term);

  if (tid == 0){
    float gp = 0.f, lp = 0.f;
    #pragma unroll
    for (int j=0;j<NBLK_SEQ;++j){ gp += wsG[b*NBLK_SEQ+j]; lp += wsL[b*NBLK_SEQ+j]; }
    int len = (int)lp;
    int last_tag = (len==0)? START_IDX : tgt[b*L_SZ + len-1];
    float goldT = gp + trans[STOP_IDX*T_SZ + last_tag];
    atomicAdd(out, (fwd - goldT) * (1.0f/B_SZ));
  }
}

// ===================== fallback: round-1 single kernel (no workspace) =====================
__global__ __launch_bounds__(1024) void crf_loss_kernel(
    const float* __restrict__ efeats, const float* __restrict__ mask,
    const int* __restrict__ tgt, const float* __restrict__ trans,
    float* __restrict__ out)
{
  __shared__ float s_trans[T_SZ*T_SZ];
  __shared__ float s_d[FB_NCH][T_SZ];
  __shared__ unsigned short s_M[FB_NCH][T_SZ*T_SZ];
  __shared__ int   s_es[FB_NCH];
  __shared__ float s_gd[FB_NCH];
  __shared__ float s_mlv[FB_NCH];

  const int tid  = threadIdx.x;
  const int b    = blockIdx.x;
  const int w    = tid >> 6;
  const int lane = tid & 63;
  const int g    = lane >> 4;
  const int c16  = lane & 15;
  const int i32  = lane & 31;

  s_trans[tid] = trans[tid];
  __syncthreads();

  int a0[4], a1[4];
  #pragma unroll
  for (int I=0; I<2; ++I){
    int row = 8*(c16>>2) + 4*I + (c16&3);
    float e[8];
    #pragma unroll
    for (int j=0;j<8;++j) e[j] = __expf(s_trans[row*T_SZ + 8*g + j]);
    int* dst = I ? a1 : a0;
    #pragma unroll
    for (int p=0;p<4;++p) dst[p] = pack_trunc(e[2*p], e[2*p+1]);
  }

  int b0[4], b1[4];
  #pragma unroll
  for (int p=0;p<4;++p){
    int s0 = 8*g + 2*p, s1 = s0+1;
    unsigned lo = (s0==c16)?0x3f80u:0u, hi = (s1==c16)?0x3f80u:0u;
    b0[p] = (int)(lo | (hi<<16));
    lo = (s0==16+c16)?0x3f80u:0u; hi = (s1==16+c16)?0x3f80u:0u;
    b1[p] = (int)(lo | (hi<<16));
  }

  const int l0 = w * FB_CLEN;
  const long fbase = ((long)b * L_SZ) * T_SZ;

  float fqv[4];
  #pragma unroll
  for (int i=0;i<4;++i) fqv[i] = efeats[fbase + (long)(l0+i)*T_SZ + i32];

  int   tA = tgt [b*L_SZ + l0 + lane];
  int   tB = tgt [b*L_SZ + l0 + 64 + lane];
  float mA = mask[b*L_SZ + l0 + lane];
  float mB = mask[b*L_SZ + l0 + 64 + lane];
  int prev = (l0==0) ? START_IDX : tgt[b*L_SZ + l0 - 1];

  int esum = 0;
  float gold = 0.f, mlen = 0.f;
  const f32x4 zf = {0.f,0.f,0.f,0.f};

  #pragma unroll 4
  for (int t=0; t<FB_CLEN; ++t){
    float fcur = fqv[t&3];
    int lpf = l0 + t + 4; lpf = (lpf < L_SZ) ? lpf : (L_SZ-1);
    fqv[t&3] = efeats[fbase + (long)lpf*T_SZ + i32];

    float mk  = uaf((unsigned)__builtin_amdgcn_readlane((int)fau((t<64)?mA:mB), t&63));
    int   cur = __builtin_amdgcn_readlane((t<64)?tA:tB, t&63);
    mlen += mk;

    if (mk > 0.f){
      if (lane < 32) s_d[w][lane] = __expf(fcur);

      f32x4 c00 = __builtin_amdgcn_mfma_f32_16x16x32_bf16(frag_of(a0), frag_of(b0), zf, 0,0,0);
      f32x4 c01 = __builtin_amdgcn_mfma_f32_16x16x32_bf16(frag_of(a0), frag_of(b1), zf, 0,0,0);
      f32x4 c10 = __builtin_amdgcn_mfma_f32_16x16x32_bf16(frag_of(a1), frag_of(b0), zf, 0,0,0);
      f32x4 c11 = __builtin_amdgcn_mfma_f32_16x16x32_bf16(frag_of(a1), frag_of(b1), zf, 0,0,0);

      const float4* dv = (const float4*)(&s_d[w][0]);
      float4 dl = dv[2*g], dh = dv[2*g+1];
      float f0=dl.x, f1=dl.y, f2=dl.z, f3=dl.w;
      float f4=dh.x, f5=dh.y, f6=dh.z, f7=dh.w;

      float m00 = c00[0]*f0;
      unsigned mb = (unsigned)__builtin_amdgcn_readfirstlane((int)fau(m00));
      int e = (int)((mb>>23)&255u) - 127;
      esum += e;
      float r = uaf((unsigned)(127-e)<<23);
      f0*=r; f1*=r; f2*=r; f3*=r; f4*=r; f5*=r; f6*=r; f7*=r;

      c00[0]*=f0; c00[1]*=f1; c00[2]*=f2; c00[3]*=f3;
      c01[0]*=f0; c01[1]*=f1; c01[2]*=f2; c01[3]*=f3;
      c10[0]*=f4; c10[1]*=f5; c10[2]*=f6; c10[3]*=f7;
      c11[0]*=f4; c11[1]*=f5; c11[2]*=f6; c11[3]*=f7;

      b0[0]=pack_trunc(c00[0],c00[1]); b0[1]=pack_trunc(c00[2],c00[3]);
      b0[2]=pack_trunc(c10[0],c10[1]); b0[3]=pack_trunc(c10[2],c10[3]);
      b1[0]=pack_trunc(c01[0],c01[1]); b1[1]=pack_trunc(c01[2],c01[3]);
      b1[2]=pack_trunc(c11[0],c11[1]); b1[3]=pack_trunc(c11[2],c11[3]);

      float tp   = s_trans[cur*T_SZ + prev];
      float emit = uaf((unsigned)__builtin_amdgcn_readlane((int)fau(fcur), cur));
      gold += tp + emit;
    }
    prev = cur;
  }

  #pragma unroll
  for (int p=0;p<4;++p){
    int s = 8*g + 2*p;
    *(int*)((char*)(&s_M[w][0]) + (((long)(c16   )*T_SZ + s) * 2)) = b0[p];
    *(int*)((char*)(&s_M[w][0]) + (((long)(16+c16)*T_SZ + s) * 2)) = b1[p];
  }
  if (lane==0){ s_es[w]=esum; s_gd[w]=gold; s_mlv[w]=mlen; }
  __syncthreads();

  if (w==0){
    int s = i32;
    float v = (s==START_IDX)?1.f:0.f;
    int E = 0;
    for (int c=0;c<FB_NCH;++c){
      float u=0.f;
      #pragma unroll 8
      for (int k=0;k<T_SZ;++k){
        float mv = uaf(((unsigned)s_M[c][k*T_SZ + s])<<16);
        float vk = uaf((unsigned)__builtin_amdgcn_readlane((int)fau(v), k));
        u = fmaf(mv, vk, u);
      }
      unsigned ub = (unsigned)__builtin_amdgcn_readfirstlane((int)fau(u));
      int eu = (int)((ub>>23)&255u)-127;
      E += s_es[c] + eu;
      v = u * uaf((unsigned)(127-eu)<<23);
    }
    float term = v * __expf(s_trans[STOP_IDX*T_SZ + s]);
    #pragma unroll
    for (int off=16; off>0; off>>=1) term += __shfl_xor(term, off, 32);
    float fwd = (float)E * 0.69314718055994530942f + __logf(term);

    float gp = (s<FB_NCH)? s_gd[s] : 0.f;
    float lp = (s<FB_NCH)? s_mlv[s] : 0.f;
    #pragma unroll
    for (int off=16; off>0; off>>=1){ gp += __shfl_xor(gp, off, 32); lp += __shfl_xor(lp, off, 32); }
    int len = (int)lp;
    int last_tag = (len==0)? START_IDX : tgt[b*L_SZ + (len-1)];
    float goldT = gp + s_trans[STOP_IDX*T_SZ + last_tag];
    if (tid==0) atomicAdd(out, (fwd - goldT) * (1.0f/B_SZ));
  }
}

extern "C" void kernel_launch(void* const* d_in, const int* in_sizes, int n_in,
                              void* d_out, int out_size, void* d_ws, size_t ws_size,
                              hipStream_t stream)
{
  const float* efeats = (const float*)d_in[0];
  const float* mask   = (const float*)d_in[1];
  const int*   tgt    = (const int*)d_in[2];
  const float* trans  = (const float*)d_in[3];
  float* out = (float*)d_out;

  const size_t needM = (size_t)NBLK_TOT * T_SZ * T_SZ * 2;   // 2 MiB
  const size_t need  = needM + (size_t)NBLK_TOT * 12;

  zero_kernel<<<dim3(1), dim3(64), 0, stream>>>(out);

  if (ws_size >= need){
    unsigned short* wsM = (unsigned short*)d_ws;
    char* p = (char*)d_ws + needM;
    int*   wsE = (int*)p;
    float* wsG = (float*)(p + (size_t)NBLK_TOT*4);
    float* wsL = (float*)(p + (size_t)NBLK_TOT*8);
    crf_chunk_kernel<<<dim3(NBLK_TOT), dim3(512), 0, stream>>>(
        efeats, mask, tgt, trans, wsM, wsE, wsG, wsL);
    crf_combine_kernel<<<dim3(B_SZ), dim3(64), 0, stream>>>(
        wsM, wsE, wsG, wsL, tgt, trans, out);
  } else {
    crf_loss_kernel<<<dim3(B_SZ), dim3(1024), 0, stream>>>(efeats, mask, tgt, trans, out);
  }
}